// Round 3
// baseline (802.211 us; speedup 1.0000x reference)
//
#include <hip/hip_runtime.h>
#include <math.h>

#define L1B 4096        // 12-bit level 1
#define L2B 512         // 9-bit level 2   (bits 19..11)
#define L3B 2048        // 11-bit level 3  (bits 10..0)
#define SLOTS 32
#define NMAX 67108864   // element count upper bound (16*2048*2048)
#define H1_BLOCKS 512
#define H2C_BLOCKS 256
#define H2W (SLOTS * L2B / 2)   // 8192 packed-u16 words
#define H1PAD (L1B + 8)         // bank-shift pad between sub-histograms
#define CCAP 8192               // compaction LDS staging capacity (keys)

// ---------------- device-global scratch ----------------
__device__ __align__(16) unsigned int g_keys[NMAX];     // compacted survivor keys
__device__ unsigned int g_nkeys;                        // zeroed each launch
__device__ unsigned int g_part1[H1_BLOCKS * L1B];       // fully overwritten
__device__ unsigned int g_r1tmp[16 * L1B];              // fully overwritten
__device__ unsigned int g_hist1[L1B];                   // fully overwritten
__device__ unsigned int g_part2[H2C_BLOCKS * H2W];      // fully overwritten
__device__ unsigned int g_r2lo[8 * H2W], g_r2hi[8 * H2W];
__device__ unsigned int g_hist2[SLOTS * L2B];           // fully overwritten
__device__ unsigned int g_hist3[SLOTS * L3B];           // zeroed each launch
__device__ unsigned char g_sid1[L1B];                   // slot1+1 per l1 bin, zeroed
__device__ unsigned char g_sid2[SLOTS * L2B];           // slot2+1, zeroed

__device__ unsigned int g_bin1[32], g_res1[32];
__device__ int          g_slot1[32];
__device__ unsigned int g_bin2[32], g_res2[32];
__device__ int          g_slot2[32];
__device__ float        g_mn[16], g_mx[16];
__device__ unsigned int g_tkey[16];

// monotone float->uint key
__device__ __forceinline__ unsigned int f2key(float f) {
    unsigned int b = __float_as_uint(f);
    return (b & 0x80000000u) ? ~b : (b | 0x80000000u);
}
__device__ __forceinline__ float key2f(unsigned int k) {
    unsigned int b = (k & 0x80000000u) ? (k & 0x7FFFFFFFu) : ~k;
    return __uint_as_float(b);
}

// ---------------- zero ----------------
__global__ void zero_scratch() {
    int i = blockIdx.x * blockDim.x + threadIdx.x;
    int stride = gridDim.x * blockDim.x;
    for (int j = i; j < SLOTS * L3B; j += stride) g_hist3[j] = 0u;
    unsigned int* s1 = (unsigned int*)g_sid1;
    for (int j = i; j < L1B / 4; j += stride) s1[j] = 0u;
    unsigned int* s2 = (unsigned int*)g_sid2;
    for (int j = i; j < SLOTS * L2B / 4; j += stride) s2[j] = 0u;
    if (i == 0) g_nkeys = 0u;
}

// ---------------- level-1 histogram ----------------
__global__ void hist1_kernel(const float4* __restrict__ x, int n4) {
    __shared__ unsigned int h[2 * H1PAD];  // 2 sub-hists by lane parity, bank-shifted
    for (int j = threadIdx.x; j < 2 * H1PAD; j += blockDim.x) h[j] = 0u;
    __syncthreads();
    unsigned int* hp = &h[(threadIdx.x & 1) * H1PAD];
    int stride = gridDim.x * blockDim.x;
    for (int i = blockIdx.x * blockDim.x + threadIdx.x; i < n4; i += stride) {
        float4 v = x[i];
        atomicAdd(&hp[f2key(v.x) >> 20], 1u);
        atomicAdd(&hp[f2key(v.y) >> 20], 1u);
        atomicAdd(&hp[f2key(v.z) >> 20], 1u);
        atomicAdd(&hp[f2key(v.w) >> 20], 1u);
    }
    __syncthreads();
    for (int j = threadIdx.x; j < L1B; j += blockDim.x)
        g_part1[blockIdx.x * L1B + j] = h[j] + h[H1PAD + j];
}

// two-stage reduce: 512 partials -> 16 groups of 32 -> final
__global__ void reduce1_s1() {
    int t = blockIdx.x * blockDim.x + threadIdx.x;  // 65536 threads
    int j = t & (L1B - 1);
    int g = t >> 12;  // 0..15
    unsigned int s = 0;
    for (int b = g * 32; b < g * 32 + 32; ++b) s += g_part1[b * L1B + j];
    g_r1tmp[g * L1B + j] = s;
}
__global__ void reduce1_s2() {
    int j = blockIdx.x * blockDim.x + threadIdx.x;  // 4096 threads
    unsigned int s = 0;
    for (int g = 0; g < 16; ++g) s += g_r1tmp[g * L1B + j];
    g_hist1[j] = s;
}

// ---------------- wave-parallel rank select ----------------
__device__ void wave_select(const unsigned int* hist, int nbins, unsigned int r,
                            unsigned int* out_bin, unsigned int* out_res) {
    int lane = threadIdx.x & 63;
    unsigned int base = 0;
    for (int k = 0; k < nbins; k += 64) {
        unsigned int v = hist[k + lane];
        unsigned int incl = v;
#pragma unroll
        for (int off = 1; off < 64; off <<= 1) {
            unsigned int t = (unsigned int)__shfl_up((int)incl, off, 64);
            if (lane >= off) incl += t;
        }
        unsigned int total = (unsigned int)__shfl((int)incl, 63, 64);
        if (r < base + total) {  // wave-uniform
            unsigned long long m = __ballot(base + incl > r);
            int fl = __ffsll((long long)m) - 1;
            unsigned int incl_fl = (unsigned int)__shfl((int)incl, fl, 64);
            unsigned int v_fl = (unsigned int)__shfl((int)v, fl, 64);
            if (lane == 0) {
                *out_bin = (unsigned int)(k + fl);
                *out_res = r - (base + incl_fl - v_fl);
            }
            return;
        }
        base += total;
    }
}

// select1 + assign1 fused: 1 block x 1024 threads (16 waves, 2 ranks each)
__global__ void select1_kernel(unsigned int n) {
    __shared__ unsigned int s_hist[L1B];
    __shared__ unsigned int s_bin[32], s_res[32];
    for (int j = threadIdx.x; j < L1B; j += blockDim.x) s_hist[j] = g_hist1[j];
    __syncthreads();
    unsigned int M = n >> 4;
    int w = threadIdx.x >> 6;
    for (int i = w; i < 32; i += 16) {
        unsigned int c = (unsigned int)(i >> 1);
        unsigned int r = (i & 1) ? ((c + 1) * M - 1u) : (c * M);
        wave_select(s_hist, L1B, r, &s_bin[i], &s_res[i]);
    }
    __syncthreads();
    if (threadIdx.x == 0) {
        unsigned int ubin[32]; int ns = 0;
        for (int i = 0; i < 32; ++i) {
            unsigned int b = s_bin[i];
            int sl = -1;
            for (int k = 0; k < ns; ++k) if (ubin[k] == b) { sl = k; break; }
            if (sl < 0) { sl = ns; ubin[ns++] = b; g_sid1[b] = (unsigned char)(sl + 1); }
            g_bin1[i] = b; g_res1[i] = s_res[i]; g_slot1[i] = sl;
        }
    }
}

// ---------------- compaction: write survivor keys ----------------
__global__ void __launch_bounds__(512) compact_kernel(const float4* __restrict__ x, int n4) {
    __shared__ unsigned int buf[CCAP];        // 32 KB
    __shared__ unsigned char sid[L1B];        // 4 KB
    __shared__ unsigned int s_cnt, s_base;
    unsigned int* sw = (unsigned int*)sid;
    for (int j = threadIdx.x; j < L1B / 4; j += blockDim.x) sw[j] = ((const unsigned int*)g_sid1)[j];
    if (threadIdx.x == 0) s_cnt = 0u;
    __syncthreads();

    int lane = threadIdx.x & 63;
    unsigned long long lanemask = (1ull << lane) - 1ull;
    int NT = gridDim.x * blockDim.x;
    int kIters = (n4 + NT - 1) / NT;
    int i0 = blockIdx.x * blockDim.x + threadIdx.x;

    for (int it = 0; it < kIters; ++it) {
        int i = i0 + it * NT;
        float4 v;
        bool inb = (i < n4);
        if (inb) v = x[i];
        float vv[4] = {v.x, v.y, v.z, v.w};
#pragma unroll
        for (int k = 0; k < 4; ++k) {
            unsigned int key = inb ? f2key(vv[k]) : 0u;
            bool act = inb && (sid[key >> 20] != 0);
            unsigned long long m = __ballot(act);
            if (m) {
                int leader = __ffsll((long long)m) - 1;
                unsigned int pos = 0;
                if (lane == leader) pos = atomicAdd(&s_cnt, (unsigned int)__popcll(m));
                pos = (unsigned int)__shfl((int)pos, leader, 64);
                if (act) buf[pos + (unsigned int)__popcll(m & lanemask)] = key;
            }
        }
        if ((it & 1) == 1) {  // max 4096 keys added between checks
            __syncthreads();
            unsigned int c = s_cnt;
            if (c > CCAP - 4096) {
                if (threadIdx.x == 0) s_base = atomicAdd(&g_nkeys, c);
                __syncthreads();
                for (unsigned int j = threadIdx.x; j < c; j += blockDim.x)
                    g_keys[s_base + j] = buf[j];
                __syncthreads();
                if (threadIdx.x == 0) s_cnt = 0u;
                __syncthreads();
            }
        }
    }
    __syncthreads();
    unsigned int c = s_cnt;
    if (c) {
        if (threadIdx.x == 0) s_base = atomicAdd(&g_nkeys, c);
        __syncthreads();
        for (unsigned int j = threadIdx.x; j < c; j += blockDim.x)
            g_keys[s_base + j] = buf[j];
    }
}

// ---------------- level-2 histogram over compacted keys ----------------
__global__ void hist2c_kernel() {
    __shared__ unsigned int h2[H2W];          // 32 KB packed u16
    __shared__ unsigned char sid[L1B];        // 4 KB
    for (int j = threadIdx.x; j < H2W; j += blockDim.x) h2[j] = 0u;
    unsigned int* sw = (unsigned int*)sid;
    for (int j = threadIdx.x; j < L1B / 4; j += blockDim.x) sw[j] = ((const unsigned int*)g_sid1)[j];
    __syncthreads();
    unsigned int nk = g_nkeys;
    unsigned int nk4 = nk >> 2;
    int stride = gridDim.x * blockDim.x;
    const uint4* k4 = (const uint4*)g_keys;
    for (unsigned int i = blockIdx.x * blockDim.x + threadIdx.x; i < nk4; i += stride) {
        uint4 kk = k4[i];
        unsigned int ks[4] = {kk.x, kk.y, kk.z, kk.w};
#pragma unroll
        for (int k = 0; k < 4; ++k) {
            unsigned int key = ks[k];
            unsigned int s = sid[key >> 20];  // guaranteed >= 1
            unsigned int c = ((s - 1) << 9) | ((key >> 11) & (L2B - 1));
            atomicAdd(&h2[c >> 1], 1u << ((c & 1) << 4));
        }
    }
    {   // tail
        unsigned int t = (unsigned int)(blockIdx.x * blockDim.x + threadIdx.x);
        unsigned int base = nk & ~3u;
        if (t < (nk & 3u)) {
            unsigned int key = g_keys[base + t];
            unsigned int s = sid[key >> 20];
            unsigned int c = ((s - 1) << 9) | ((key >> 11) & (L2B - 1));
            atomicAdd(&h2[c >> 1], 1u << ((c & 1) << 4));
        }
    }
    __syncthreads();
    for (int j = threadIdx.x; j < H2W; j += blockDim.x)
        g_part2[blockIdx.x * H2W + j] = h2[j];
}

__global__ void reduce2_s1() {
    int t = blockIdx.x * blockDim.x + threadIdx.x;  // 65536 threads
    int w = t & (H2W - 1);
    int g = t >> 13;  // 0..7, each sums 32 blocks
    unsigned int lo = 0, hi = 0;
    for (int b = g * 32; b < g * 32 + 32; ++b) {
        unsigned int u = g_part2[b * H2W + w];
        lo += u & 0xFFFFu; hi += u >> 16;
    }
    g_r2lo[g * H2W + w] = lo;
    g_r2hi[g * H2W + w] = hi;
}
__global__ void reduce2_s2() {
    int c = blockIdx.x * blockDim.x + threadIdx.x;  // 16384 threads
    int w = c >> 1, half = c & 1;
    unsigned int s = 0;
    if (half) { for (int g = 0; g < 8; ++g) s += g_r2hi[g * H2W + w]; }
    else      { for (int g = 0; g < 8; ++g) s += g_r2lo[g * H2W + w]; }
    g_hist2[c] = s;
}

// select2 + assign2 fused
__global__ void select2_kernel() {
    __shared__ unsigned int s_bin[32], s_res[32];
    int w = threadIdx.x >> 6;
    for (int i = w; i < 32; i += 16) {
        int s = g_slot1[i];
        wave_select(g_hist2 + s * L2B, L2B, g_res1[i], &s_bin[i], &s_res[i]);
    }
    __syncthreads();
    if (threadIdx.x == 0) {
        int upos[32]; int ns = 0;
        for (int i = 0; i < 32; ++i) {
            int p = g_slot1[i] * L2B + (int)s_bin[i];
            int sl = -1;
            for (int k = 0; k < ns; ++k) if (upos[k] == p) { sl = k; break; }
            if (sl < 0) { sl = ns; upos[ns++] = p; g_sid2[p] = (unsigned char)(sl + 1); }
            g_bin2[i] = s_bin[i]; g_res2[i] = s_res[i]; g_slot2[i] = sl;
        }
    }
}

// ---------------- level-3 histogram over compacted keys ----------------
__global__ void hist3c_kernel() {
    __shared__ unsigned char sid1[L1B];          // 4 KB
    __shared__ unsigned char sid2[SLOTS * L2B];  // 16 KB
    unsigned int* s1w = (unsigned int*)sid1;
    for (int j = threadIdx.x; j < L1B / 4; j += blockDim.x) s1w[j] = ((const unsigned int*)g_sid1)[j];
    unsigned int* s2w = (unsigned int*)sid2;
    for (int j = threadIdx.x; j < SLOTS * L2B / 4; j += blockDim.x) s2w[j] = ((const unsigned int*)g_sid2)[j];
    __syncthreads();
    unsigned int nk = g_nkeys;
    unsigned int nk4 = nk >> 2;
    int stride = gridDim.x * blockDim.x;
    const uint4* k4 = (const uint4*)g_keys;
    for (unsigned int i = blockIdx.x * blockDim.x + threadIdx.x; i < nk4; i += stride) {
        uint4 kk = k4[i];
        unsigned int ks[4] = {kk.x, kk.y, kk.z, kk.w};
#pragma unroll
        for (int k = 0; k < 4; ++k) {
            unsigned int key = ks[k];
            unsigned int s1 = sid1[key >> 20];
            unsigned int s2 = sid2[((s1 - 1) << 9) | ((key >> 11) & (L2B - 1))];
            if (s2) atomicAdd(&g_hist3[((s2 - 1) << 11) | (key & (L3B - 1))], 1u);
        }
    }
    {   // tail
        unsigned int t = (unsigned int)(blockIdx.x * blockDim.x + threadIdx.x);
        unsigned int base = nk & ~3u;
        if (t < (nk & 3u)) {
            unsigned int key = g_keys[base + t];
            unsigned int s1 = sid1[key >> 20];
            unsigned int s2 = sid2[((s1 - 1) << 9) | ((key >> 11) & (L2B - 1))];
            if (s2) atomicAdd(&g_hist3[((s2 - 1) << 11) | (key & (L3B - 1))], 1u);
        }
    }
}

// select3 + finalize fused
__global__ void select3_kernel() {
    __shared__ unsigned int s_bin[32], s_res[32];
    int w = threadIdx.x >> 6;
    for (int i = w; i < 32; i += 16) {
        int s2 = g_slot2[i];
        wave_select(g_hist3 + s2 * L3B, L3B, g_res2[i], &s_bin[i], &s_res[i]);
    }
    __syncthreads();
    if (threadIdx.x < 16) {
        int c = threadIdx.x;
        unsigned int klo = (g_bin1[2 * c] << 20) | (g_bin2[2 * c] << 11) | s_bin[2 * c];
        unsigned int khi = (g_bin1[2 * c + 1] << 20) | (g_bin2[2 * c + 1] << 11) | s_bin[2 * c + 1];
        g_mn[c] = key2f(klo);
        g_mx[c] = key2f(khi);
        g_tkey[c] = (c == 0) ? 0u : klo;
    }
}

// ---------------- final quantization ----------------
__global__ void quant_kernel(const float4* __restrict__ x, float4* __restrict__ out, int n4) {
    __shared__ float s_mn[16], s_mx[16];
    __shared__ unsigned int s_t[16];
    if (threadIdx.x < 16) {
        s_mn[threadIdx.x] = g_mn[threadIdx.x];
        s_mx[threadIdx.x] = g_mx[threadIdx.x];
        s_t[threadIdx.x]  = g_tkey[threadIdx.x];
    }
    __syncthreads();
    int stride = gridDim.x * blockDim.x;
    for (int i = blockIdx.x * blockDim.x + threadIdx.x; i < n4; i += stride) {
        float4 v = x[i];
        float r[4] = {v.x, v.y, v.z, v.w};
#pragma unroll
        for (int k = 0; k < 4; ++k) {
            float xv = r[k];
            unsigned int key = f2key(xv);
            int c = (key >= s_t[8]) ? 8 : 0;
            if (key >= s_t[c + 4]) c += 4;
            if (key >= s_t[c + 2]) c += 2;
            if (key >= s_t[c + 1]) c += 1;
            float mn = s_mn[c], mx = s_mx[c];
            float outv;
            if (mn == mx) {
                outv = xv;
            } else {
                float st = (mx - mn) / 15.0f;
                if (st == 0.0f) st = 1.0f;
                float q = rintf((xv - mn) / st);
                outv = __fadd_rn(__fmul_rn(q, st), mn);  // match np: mul then add, no fma
            }
            r[k] = outv;
        }
        out[i] = make_float4(r[0], r[1], r[2], r[3]);
    }
}

// ---------------- launch ----------------
extern "C" void kernel_launch(void* const* d_in, const int* in_sizes, int n_in,
                              void* d_out, int out_size, void* d_ws, size_t ws_size,
                              hipStream_t stream) {
    const float* x = (const float*)d_in[0];
    float* out = (float*)d_out;
    int n  = in_sizes[0];
    int n4 = n / 4;

    zero_scratch<<<128, 256, 0, stream>>>();
    hist1_kernel<<<H1_BLOCKS, 512, 0, stream>>>((const float4*)x, n4);
    reduce1_s1<<<256, 256, 0, stream>>>();
    reduce1_s2<<<16, 256, 0, stream>>>();
    select1_kernel<<<1, 1024, 0, stream>>>((unsigned int)n);
    compact_kernel<<<512, 512, 0, stream>>>((const float4*)x, n4);
    hist2c_kernel<<<H2C_BLOCKS, 256, 0, stream>>>();
    reduce2_s1<<<256, 256, 0, stream>>>();
    reduce2_s2<<<64, 256, 0, stream>>>();
    select2_kernel<<<1, 1024, 0, stream>>>();
    hist3c_kernel<<<256, 256, 0, stream>>>();
    select3_kernel<<<1, 1024, 0, stream>>>();
    quant_kernel<<<4096, 256, 0, stream>>>((const float4*)x, (float4*)out, n4);
}